// Round 19
// baseline (186.538 us; speedup 1.0000x reference)
//
#include <hip/hip_runtime.h>
#include <hip/hip_bf16.h>
#include <cstdint>
#include <cstddef>

// Problem dims (fixed)
#define B_   4
#define N_   1024
#define C_   768
#define H_   12
#define D_   64
#define HID_ 3072
#define M_   4096  // B*N

typedef __attribute__((ext_vector_type(8))) short short8;
typedef __attribute__((ext_vector_type(8))) unsigned short ushort8;
typedef __attribute__((ext_vector_type(4))) float f32x4;

__device__ __forceinline__ void gload16(const void* g, void* l) {
  __builtin_amdgcn_global_load_lds(
      (const __attribute__((address_space(1))) void*)g,
      (__attribute__((address_space(3))) void*)l, 16, 0, 0);
}

__device__ __forceinline__ unsigned short f2bf(float f) {
  __hip_bfloat16 h = __float2bfloat16(f);
  return __builtin_bit_cast(unsigned short, h);
}
__device__ __forceinline__ float bf2f(unsigned short u) {
  unsigned int x = ((unsigned int)u) << 16;
  return __builtin_bit_cast(float, x);
}
__device__ __forceinline__ float ex2(float x) {
  float r;
  asm("v_exp_f32 %0, %1" : "=v"(r) : "v"(x));
  return r;
}
__device__ __forceinline__ float frcp(float x) {
  float r;
  asm("v_rcp_f32 %0, %1" : "=v"(r) : "v"(x));
  return r;
}

// ---------------- merged prologue: weight transpose + LN1 ----------------
__global__ __launch_bounds__(256) void prologue_kernel(
    const float* __restrict__ qkv_w, const float* __restrict__ proj_w,
    const float* __restrict__ fc1_w, const float* __restrict__ fc2_w,
    unsigned short* __restrict__ wt_qkv, unsigned short* __restrict__ wt_proj,
    unsigned short* __restrict__ wt_fc1, unsigned short* __restrict__ wt_fc2,
    const float* __restrict__ x, const float* __restrict__ n1_w,
    const float* __restrict__ n1_b, unsigned short* __restrict__ h1) {
  const int bid = blockIdx.x;
  const int t = threadIdx.x;
  if (bid >= 6912) {
    __shared__ float sbuf[8];
    const int row = bid - 6912;
    const float* xr = x + (size_t)row * C_;
    float v0 = xr[t], v1 = xr[t + 256], v2 = xr[t + 512];
    float s = v0 + v1 + v2;
    float ss = v0 * v0 + v1 * v1 + v2 * v2;
#pragma unroll
    for (int m = 32; m >= 1; m >>= 1) {
      s += __shfl_xor(s, m);
      ss += __shfl_xor(ss, m);
    }
    const int wave = t >> 6, lane = t & 63;
    if (lane == 0) { sbuf[wave] = s; sbuf[4 + wave] = ss; }
    __syncthreads();
    s = sbuf[0] + sbuf[1] + sbuf[2] + sbuf[3];
    ss = sbuf[4] + sbuf[5] + sbuf[6] + sbuf[7];
    const float mu = s * (1.f / C_);
    const float var = ss * (1.f / C_) - mu * mu;
    const float rstd = rsqrtf(var + 1e-6f);
    unsigned short* o = h1 + (size_t)row * C_;
    o[t]       = f2bf((v0 - mu) * rstd * n1_w[t]       + n1_b[t]);
    o[t + 256] = f2bf((v1 - mu) * rstd * n1_w[t + 256] + n1_b[t + 256]);
    o[t + 512] = f2bf((v2 - mu) * rstd * n1_w[t + 512] + n1_b[t + 512]);
    return;
  }
  __shared__ float tile[32][33];
  const float* W;
  unsigned short* Wt;
  int K, Nn, bx, by;
  if (bid < 1728) {
    W = qkv_w; Wt = wt_qkv; K = 768; Nn = 2304;
    bx = bid % 72; by = bid / 72;
  } else if (bid < 1728 + 576) {
    const int i = bid - 1728;
    W = proj_w; Wt = wt_proj; K = 768; Nn = 768;
    bx = i % 24; by = i / 24;
  } else if (bid < 1728 + 576 + 2304) {
    const int i = bid - (1728 + 576);
    W = fc1_w; Wt = wt_fc1; K = 768; Nn = 3072;
    bx = i % 96; by = i / 96;
  } else {
    const int i = bid - (1728 + 576 + 2304);
    W = fc2_w; Wt = wt_fc2; K = 3072; Nn = 768;
    bx = i % 24; by = i / 24;
  }
  const int tx = t & 31, ty = t >> 5;
  const int n0 = bx * 32, k0 = by * 32;
#pragma unroll
  for (int i = 0; i < 32; i += 8)
    tile[ty + i][tx] = W[(size_t)(k0 + ty + i) * Nn + n0 + tx];
  __syncthreads();
#pragma unroll
  for (int i = 0; i < 32; i += 8)
    Wt[(size_t)(n0 + ty + i) * K + k0 + tx] = f2bf(tile[tx][ty + i]);
}

// ---------------- LayerNorm (fp32 in -> bf16 out) ----------------
__global__ __launch_bounds__(256) void ln_kernel(const float* __restrict__ x,
                                                 const float* __restrict__ w,
                                                 const float* __restrict__ b,
                                                 unsigned short* __restrict__ out) {
  __shared__ float sbuf[8];
  const int row = blockIdx.x;
  const int t = threadIdx.x;
  const float* xr = x + (size_t)row * C_;
  float v0 = xr[t], v1 = xr[t + 256], v2 = xr[t + 512];
  float s = v0 + v1 + v2;
  float ss = v0 * v0 + v1 * v1 + v2 * v2;
#pragma unroll
  for (int m = 32; m >= 1; m >>= 1) {
    s += __shfl_xor(s, m);
    ss += __shfl_xor(ss, m);
  }
  const int wave = t >> 6, lane = t & 63;
  if (lane == 0) { sbuf[wave] = s; sbuf[4 + wave] = ss; }
  __syncthreads();
  s = sbuf[0] + sbuf[1] + sbuf[2] + sbuf[3];
  ss = sbuf[4] + sbuf[5] + sbuf[6] + sbuf[7];
  const float mu = s * (1.f / C_);
  const float var = ss * (1.f / C_) - mu * mu;
  const float rstd = rsqrtf(var + 1e-6f);
  unsigned short* o = out + (size_t)row * C_;
  o[t]       = f2bf((v0 - mu) * rstd * w[t]       + b[t]);
  o[t + 256] = f2bf((v1 - mu) * rstd * w[t + 256] + b[t + 256]);
  o[t + 512] = f2bf((v2 - mu) * rstd * w[t + 512] + b[t + 512]);
}

// ---------------- GEMM: C = A[M,K] * Bt[N,K]^T + bias, fused epilogue ----------
// Waves arranged WM x (4/WM); per-wave output = MR*16 rows x 64 cols.
// BM = WM*MR*16, BN = (4/WM)*64. BK=32. 3 LDS buffers, depth-2 counted-vmcnt
// prefetch, raw s_barrier, setprio, 2-way-optimal LDS XOR swizzle.
//   qkv/fc1: <2,2> -> 64x128 (4 blocks/CU). proj/fc2: <1,4> -> 64x64.
template <int MR, int WM, bool GELU, bool RES, bool OUTF, bool OUTB>
__global__ __launch_bounds__(256) void gemm_bt(const unsigned short* __restrict__ A,
                                               const unsigned short* __restrict__ Bt,
                                               const float* __restrict__ bias,
                                               const float* __restrict__ res,
                                               float* __restrict__ outF,
                                               unsigned short* __restrict__ outB,
                                               int M, int Nn, int K) {
  constexpr int WN = 4 / WM;
  constexpr int BM = WM * MR * 16;
  constexpr int BN = WN * 64;
  constexpr int ACALLS = BM / 64;  // 4096B gload calls per A half-stage
  constexpr int BCALLS = BN / 64;
  constexpr int L = ACALLS + BCALLS;  // loads per stage
  __shared__ unsigned short As[3][BM * 32];
  __shared__ unsigned short Bs[3][BN * 32];
  const int t = threadIdx.x;
  const int lane = t & 63;
  const int wave = t >> 6;
  const int wm = wave / WN, wn = wave % WN;
  const int r15 = lane & 15, g = lane >> 4;

  constexpr int SPX = (BM == 128) ? 4 : 8;   // bm stripes per xcd (M == 4096)
  constexpr int LGS = (BM == 128) ? 2 : 3;
  const int orig = blockIdx.y * gridDim.x + blockIdx.x;
  const int xcd = orig & 7;
  const int j = orig >> 3;
  const int bm = xcd * SPX + (j & (SPX - 1));
  const int bn = j >> LGS;

  f32x4 acc[MR][4];
#pragma unroll
  for (int m = 0; m < MR; ++m)
#pragma unroll
    for (int n = 0; n < 4; ++n) acc[m][n] = (f32x4){0.f, 0.f, 0.f, 0.f};

  const int srow = t >> 2;
  const int schunk = (t & 3) ^ ((t >> 3) & 3);
  const unsigned short* ga0 = A + (size_t)(bm * BM + srow) * K + schunk * 8;
  const unsigned short* gb0 = Bt + (size_t)(bn * BN + srow) * K + schunk * 8;

#define GSTAGE(kt_, buf_)                                                      \
  {                                                                            \
    const unsigned short* ga = ga0 + (kt_)*32;                                 \
    const unsigned short* gb = gb0 + (kt_)*32;                                 \
    _Pragma("unroll") for (int c = 0; c < ACALLS; ++c)                         \
        gload16(ga + (size_t)(c * 64) * K,                                     \
                (char*)As[buf_] + c * 4096 + wave * 1024);                     \
    _Pragma("unroll") for (int c = 0; c < BCALLS; ++c)                         \
        gload16(gb + (size_t)(c * 64) * K,                                     \
                (char*)Bs[buf_] + c * 4096 + wave * 1024);                     \
  }

  const int nk = K >> 5;
  GSTAGE(0, 0);
  GSTAGE(1, 1);

  int aoff[MR], boff[4];
#pragma unroll
  for (int m = 0; m < MR; ++m) {
    const int ar = wm * (MR * 16) + m * 16 + r15;
    aoff[m] = ar * 32 + (g ^ ((ar >> 1) & 3)) * 8;
  }
#pragma unroll
  for (int n = 0; n < 4; ++n) {
    const int rn = wn * 64 + n * 16 + r15;
    boff[n] = rn * 32 + (g ^ ((rn >> 1) & 3)) * 8;
  }

  int rd = 0;
  for (int kt = 0; kt < nk; ++kt) {
    const int rem = nk - kt;
    if (rem >= 2) {
      if constexpr (L == 4) asm volatile("s_waitcnt vmcnt(4)" ::: "memory");
      else if constexpr (L == 3) asm volatile("s_waitcnt vmcnt(3)" ::: "memory");
      else asm volatile("s_waitcnt vmcnt(2)" ::: "memory");
    } else {
      asm volatile("s_waitcnt vmcnt(0)" ::: "memory");
    }
    __builtin_amdgcn_s_barrier();

    short8 af[MR], bf[4];
#pragma unroll
    for (int m = 0; m < MR; ++m)
      af[m] = *(const short8*)(As[rd] + aoff[m]);
#pragma unroll
    for (int n = 0; n < 4; ++n)
      bf[n] = *(const short8*)(Bs[rd] + boff[n]);

    if (kt + 2 < nk) {
      const int wr = (rd + 2 >= 3) ? rd - 1 : rd + 2;  // (kt+2)%3
      GSTAGE(kt + 2, wr);
    }

    asm volatile("s_waitcnt lgkmcnt(0)" ::: "memory");
    __builtin_amdgcn_sched_barrier(0);
    __builtin_amdgcn_s_setprio(1);
#pragma unroll
    for (int m = 0; m < MR; ++m)
#pragma unroll
      for (int n = 0; n < 4; ++n)
        acc[m][n] = __builtin_amdgcn_mfma_f32_16x16x32_bf16(af[m], bf[n], acc[m][n], 0, 0, 0);
    __builtin_amdgcn_s_setprio(0);
    rd = (rd == 2) ? 0 : rd + 1;
  }
#undef GSTAGE

#pragma unroll
  for (int m = 0; m < MR; ++m) {
#pragma unroll
    for (int n = 0; n < 4; ++n) {
#pragma unroll
      for (int r = 0; r < 4; ++r) {
        const int row = bm * BM + wm * (MR * 16) + m * 16 + g * 4 + r;
        const int col = bn * BN + wn * 64 + n * 16 + r15;
        float v = acc[m][n][r] + bias[col];
        if (GELU) v = 0.5f * v * (1.f + erff(v * 0.70710678118654752f));
        if (RES) v += res[(size_t)row * Nn + col];
        if (OUTF) outF[(size_t)row * Nn + col] = v;
        if (OUTB) outB[(size_t)row * Nn + col] = f2bf(v);
      }
    }
  }
}

// ---------------- fused biased attention (R17: R14 kernel + XCD bh-affinity) --
__global__ __launch_bounds__(256) void attn_kernel(const unsigned short* __restrict__ qkv,
                                                   const float* __restrict__ pbias,
                                                   unsigned short* __restrict__ o) {
  __shared__ unsigned short Ks[2][64 * 64];
  __shared__ unsigned short Vt[64 * 64];
  __shared__ unsigned short Ps[4][16 * 64];
  const int t = threadIdx.x, lane = t & 63, wave = t >> 6;
  const int f = blockIdx.y * gridDim.x + blockIdx.x;  // 0..767
  const int xcd = f & 7;
  const int j = f >> 3;                               // 0..95
  const int bh = xcd * 6 + (j % 6);
  const int q0 = (j / 6) * 64;
  const int b = bh / H_, h = bh % H_;
  const int r15 = lane & 15, g = lane >> 4;
  const int qrow = q0 + wave * 16;
  const float LOG2E = 1.44269504088896f;
  const float QS = 0.125f * 1.44269504088896f;  // SCALE * log2(e)
  const int NT = N_ / 64;

  short8 aq[2];
  {
    const unsigned short* qp =
        qkv + (size_t)(b * N_ + qrow + r15) * (3 * C_) + h * D_ + g * 8;
    const ushort8 r0 = *(const ushort8*)qp;
    const ushort8 r1 = *(const ushort8*)(qp + 32);
#pragma unroll
    for (int jj = 0; jj < 8; ++jj) {
      aq[0][jj] = (short)f2bf(bf2f(r0[jj]) * QS);
      aq[1][jj] = (short)f2bf(bf2f(r1[jj]) * QS);
    }
  }
  short8 ones;
#pragma unroll
  for (int jj = 0; jj < 8; ++jj) ones[jj] = (short)0x3F80;

  f32x4 oacc[4], lacc;
#pragma unroll
  for (int n = 0; n < 4; ++n) oacc[n] = (f32x4){0.f, 0.f, 0.f, 0.f};
  lacc = (f32x4){0.f, 0.f, 0.f, 0.f};
  float m_run[4];
#pragma unroll
  for (int r = 0; r < 4; ++r) m_run[r] = -1e30f;

  const unsigned short* kbase = qkv + (size_t)b * N_ * (3 * C_) + C_ + h * D_;
  const unsigned short* vbase = qkv + (size_t)b * N_ * (3 * C_) + 2 * C_ + h * D_;

  const float* bp[4];
#pragma unroll
  for (int r = 0; r < 4; ++r)
    bp[r] = pbias + (size_t)b * N_ * N_ + (size_t)(qrow + g * 4 + r) * N_ + r15;

  const int krow = t >> 3;
  const int kchunk = (t & 7) ^ (krow & 7);
  const int vp = t & 31;
  const int vq = t >> 5;
  const int vkey = vp * 2, vd0 = vq * 8;

#define KSTAGE(kb_, nb_)                                                       \
  {                                                                            \
    const unsigned short* kg =                                                 \
        kbase + (size_t)((kb_)*64 + krow) * (3 * C_) + kchunk * 8;             \
    gload16(kg, (char*)Ks[nb_] + wave * 1024);                                 \
    gload16(kg + (size_t)32 * (3 * C_), (char*)Ks[nb_] + wave * 1024 + 4096);  \
  }

#define VWRITE(va_, vb_)                                                             \
  {                                                                                  \
    char* vdst = (char*)Vt;                                                          \
    _Pragma("unroll") for (int jj = 0; jj < 8; ++jj) {                               \
      const int d = vd0 + jj;                                                        \
      const unsigned int pack =                                                      \
          (unsigned int)(va_)[jj] | ((unsigned int)(vb_)[jj] << 16);                 \
      *(unsigned int*)(vdst + d * 128 + (((vp >> 2) ^ (d & 7)) << 4) +               \
                       (vp & 3) * 4) = pack;                                         \
    }                                                                                \
  }

  KSTAGE(0, 0);
  ushort8 va, vb2;
  {
    const unsigned short* vg = vbase + (size_t)vkey * (3 * C_) + vd0;
    va = *(const ushort8*)vg;
    vb2 = *(const ushort8*)(vg + 3 * C_);
  }
  float bcur[4][4], bnext[4][4];
#pragma unroll
  for (int n = 0; n < 4; ++n)
#pragma unroll
    for (int r = 0; r < 4; ++r) bcur[n][r] = bp[r][n * 16];

  for (int kb = 0; kb < NT; ++kb) {
    const int cur = kb & 1;
    __syncthreads();  // K[kb] staged & visible; all waves' PV[kb-1] complete

    VWRITE(va, vb2);

    const bool more = (kb + 1 < NT);
    if (more) {
      KSTAGE(kb + 1, cur ^ 1);
      const unsigned short* vg =
          vbase + (size_t)((kb + 1) * 64 + vkey) * (3 * C_) + vd0;
      va = *(const ushort8*)vg;
      vb2 = *(const ushort8*)(vg + 3 * C_);
#pragma unroll
      for (int n = 0; n < 4; ++n)
#pragma unroll
        for (int r = 0; r < 4; ++r) bnext[n][r] = bp[r][64 + n * 16];
    }
#pragma unroll
    for (int r = 0; r < 4; ++r) bp[r] += 64;

    const unsigned short* Ksc = Ks[cur];
    f32x4 sacc[4];
#pragma unroll
    for (int n = 0; n < 4; ++n) sacc[n] = (f32x4){0.f, 0.f, 0.f, 0.f};
    __builtin_amdgcn_s_setprio(1);
#pragma unroll
    for (int kk = 0; kk < 2; ++kk) {
#pragma unroll
      for (int n = 0; n < 4; ++n) {
        short8 bk = *(const short8*)(Ksc + (n * 16 + r15) * 64 +
                                     (((kk * 4 + g) ^ (r15 & 7)) << 3));
        sacc[n] = __builtin_amdgcn_mfma_f32_16x16x32_bf16(aq[kk], bk, sacc[n], 0, 0, 0);
      }
    }
    __builtin_amdgcn_s_setprio(0);

    float p[4][4], tm[4];
#pragma unroll
    for (int n = 0; n < 4; ++n)
#pragma unroll
      for (int r = 0; r < 4; ++r)
        p[n][r] = fmaf(bcur[n][r], LOG2E, sacc[n][r]);
#pragma unroll
    for (int r = 0; r < 4; ++r)
      tm[r] = fmaxf(fmaxf(p[0][r], p[1][r]), fmaxf(p[2][r], p[3][r]));
#pragma unroll
    for (int r = 0; r < 4; ++r) {
      tm[r] = fmaxf(tm[r], __shfl_xor(tm[r], 1));
      tm[r] = fmaxf(tm[r], __shfl_xor(tm[r], 2));
      tm[r] = fmaxf(tm[r], __shfl_xor(tm[r], 4));
      tm[r] = fmaxf(tm[r], __shfl_xor(tm[r], 8));
    }
    int need = 0;
#pragma unroll
    for (int r = 0; r < 4; ++r) need |= (tm[r] > m_run[r] + 8.0f);
    if (__any(need)) {
#pragma unroll
      for (int r = 0; r < 4; ++r) {
        const float mn = fmaxf(m_run[r], tm[r]);
        const float corr = ex2(m_run[r] - mn);
        m_run[r] = mn;
        lacc[r] *= corr;
#pragma unroll
        for (int n = 0; n < 4; ++n) oacc[n][r] *= corr;
      }
    }
#pragma unroll
    for (int n = 0; n < 4; ++n)
#pragma unroll
      for (int r = 0; r < 4; ++r) p[n][r] = ex2(p[n][r] - m_run[r]);

    unsigned short* Psw = Ps[wave];
#pragma unroll
    for (int n = 0; n < 4; ++n)
#pragma unroll
      for (int r = 0; r < 4; ++r) {
        const int row = g * 4 + r, col = n * 16 + r15;
        Psw[row * 64 + (((col >> 3) ^ (row & 7)) << 3) + (col & 7)] = f2bf(p[n][r]);
      }

    asm volatile("s_waitcnt lgkmcnt(0)" ::: "memory");
    __builtin_amdgcn_s_barrier();
    __builtin_amdgcn_sched_barrier(0);

    __builtin_amdgcn_s_setprio(1);
#pragma unroll
    for (int kk = 0; kk < 2; ++kk) {
      short8 ap = *(const short8*)(Psw + r15 * 64 + (((kk * 4 + g) ^ (r15 & 7)) << 3));
      lacc = __builtin_amdgcn_mfma_f32_16x16x32_bf16(ap, ones, lacc, 0, 0, 0);
#pragma unroll
      for (int n = 0; n < 4; ++n) {
        short8 bv = *(const short8*)(Vt + (n * 16 + r15) * 64 +
                                     (((kk * 4 + g) ^ (r15 & 7)) << 3));
        oacc[n] = __builtin_amdgcn_mfma_f32_16x16x32_bf16(ap, bv, oacc[n], 0, 0, 0);
      }
    }
    __builtin_amdgcn_s_setprio(0);

    if (more) {
#pragma unroll
      for (int n = 0; n < 4; ++n)
#pragma unroll
        for (int r = 0; r < 4; ++r) bcur[n][r] = bnext[n][r];
    }
  }
#undef KSTAGE
#undef VWRITE

  float rl[4];
#pragma unroll
  for (int r = 0; r < 4; ++r) rl[r] = frcp(lacc[r]);
#pragma unroll
  for (int n = 0; n < 4; ++n) {
#pragma unroll
    for (int r = 0; r < 4; ++r) {
      const int row = qrow + g * 4 + r;
      const float v = oacc[n][r] * rl[r];
      o[(size_t)(b * N_ + row) * C_ + h * D_ + n * 16 + r15] = f2bf(v);
    }
  }
}

// ---------------- launcher ----------------
extern "C" void kernel_launch(void* const* d_in, const int* in_sizes, int n_in,
                              void* d_out, int out_size, void* d_ws, size_t ws_size,
                              hipStream_t stream) {
  const float* x      = (const float*)d_in[0];
  const float* pbias  = (const float*)d_in[1];
  const float* qkv_w  = (const float*)d_in[2];
  const float* qkv_b  = (const float*)d_in[3];
  const float* proj_w = (const float*)d_in[4];
  const float* proj_b = (const float*)d_in[5];
  const float* n1_w   = (const float*)d_in[6];
  const float* n1_b   = (const float*)d_in[7];
  const float* n2_w   = (const float*)d_in[8];
  const float* n2_b   = (const float*)d_in[9];
  const float* fc1_w  = (const float*)d_in[10];
  const float* fc1_b  = (const float*)d_in[11];
  const float* fc2_w  = (const float*)d_in[12];
  const float* fc2_b  = (const float*)d_in[13];
  float* out = (float*)d_out;

  char* ws = (char*)d_ws;
  unsigned short* wt_qkv  = (unsigned short*)(ws + 0);          // 2304x768 bf16
  unsigned short* wt_proj = (unsigned short*)(ws + 3538944);    // 768x768
  unsigned short* wt_fc1  = (unsigned short*)(ws + 4718592);    // 3072x768
  unsigned short* wt_fc2  = (unsigned short*)(ws + 9437184);    // 768x3072
  float*          x2      = (float*)(ws + 14155776);            // 4096x768 fp32
  unsigned short* h1      = (unsigned short*)(ws + 26738688);   // 4096x768 bf16
  unsigned short* qkvb    = (unsigned short*)(ws + 33030144);   // 4096x2304 bf16

  prologue_kernel<<<6912 + 4096, 256, 0, stream>>>(
      qkv_w, proj_w, fc1_w, fc2_w, wt_qkv, wt_proj, wt_fc1, wt_fc2,
      x, n1_w, n1_b, h1);

  gemm_bt<2, 2, false, false, false, true><<<dim3(64, 18), 256, 0, stream>>>(
      h1, wt_qkv, qkv_b, nullptr, nullptr, qkvb, M_, 3 * C_, C_);
  attn_kernel<<<dim3(N_ / 64, B_ * H_), 256, 0, stream>>>(qkvb, pbias, h1);
  gemm_bt<1, 4, false, true, true, false><<<dim3(64, 12), 256, 0, stream>>>(
      h1, wt_proj, proj_b, x, x2, nullptr, M_, C_, C_);
  ln_kernel<<<M_, 256, 0, stream>>>(x2, n2_w, n2_b, h1);
  gemm_bt<2, 2, true, false, false, true><<<dim3(64, 24), 256, 0, stream>>>(
      h1, wt_fc1, fc1_b, nullptr, nullptr, qkvb, M_, HID_, C_);
  gemm_bt<1, 4, false, true, true, false><<<dim3(64, 12), 256, 0, stream>>>(
      qkvb, wt_fc2, fc2_b, x2, out, nullptr, M_, C_, HID_);
}

// Round 20
// 172.804 us; speedup vs baseline: 1.0795x; 1.0795x over previous
//
#include <hip/hip_runtime.h>
#include <hip/hip_bf16.h>
#include <cstdint>
#include <cstddef>

// Problem dims (fixed)
#define B_   4
#define N_   1024
#define C_   768
#define H_   12
#define D_   64
#define HID_ 3072
#define M_   4096  // B*N

typedef __attribute__((ext_vector_type(8))) short short8;
typedef __attribute__((ext_vector_type(8))) unsigned short ushort8;
typedef __attribute__((ext_vector_type(4))) float f32x4;

__device__ __forceinline__ void gload16(const void* g, void* l) {
  __builtin_amdgcn_global_load_lds(
      (const __attribute__((address_space(1))) void*)g,
      (__attribute__((address_space(3))) void*)l, 16, 0, 0);
}

__device__ __forceinline__ unsigned short f2bf(float f) {
  __hip_bfloat16 h = __float2bfloat16(f);
  return __builtin_bit_cast(unsigned short, h);
}
__device__ __forceinline__ float bf2f(unsigned short u) {
  unsigned int x = ((unsigned int)u) << 16;
  return __builtin_bit_cast(float, x);
}
__device__ __forceinline__ float ex2(float x) {
  float r;
  asm("v_exp_f32 %0, %1" : "=v"(r) : "v"(x));
  return r;
}
__device__ __forceinline__ float frcp(float x) {
  float r;
  asm("v_rcp_f32 %0, %1" : "=v"(r) : "v"(x));
  return r;
}

// ---------------- merged prologue: weight transpose + LN1 ----------------
__global__ __launch_bounds__(256) void prologue_kernel(
    const float* __restrict__ qkv_w, const float* __restrict__ proj_w,
    const float* __restrict__ fc1_w, const float* __restrict__ fc2_w,
    unsigned short* __restrict__ wt_qkv, unsigned short* __restrict__ wt_proj,
    unsigned short* __restrict__ wt_fc1, unsigned short* __restrict__ wt_fc2,
    const float* __restrict__ x, const float* __restrict__ n1_w,
    const float* __restrict__ n1_b, unsigned short* __restrict__ h1) {
  const int bid = blockIdx.x;
  const int t = threadIdx.x;
  if (bid >= 6912) {
    __shared__ float sbuf[8];
    const int row = bid - 6912;
    const float* xr = x + (size_t)row * C_;
    float v0 = xr[t], v1 = xr[t + 256], v2 = xr[t + 512];
    float s = v0 + v1 + v2;
    float ss = v0 * v0 + v1 * v1 + v2 * v2;
#pragma unroll
    for (int m = 32; m >= 1; m >>= 1) {
      s += __shfl_xor(s, m);
      ss += __shfl_xor(ss, m);
    }
    const int wave = t >> 6, lane = t & 63;
    if (lane == 0) { sbuf[wave] = s; sbuf[4 + wave] = ss; }
    __syncthreads();
    s = sbuf[0] + sbuf[1] + sbuf[2] + sbuf[3];
    ss = sbuf[4] + sbuf[5] + sbuf[6] + sbuf[7];
    const float mu = s * (1.f / C_);
    const float var = ss * (1.f / C_) - mu * mu;
    const float rstd = rsqrtf(var + 1e-6f);
    unsigned short* o = h1 + (size_t)row * C_;
    o[t]       = f2bf((v0 - mu) * rstd * n1_w[t]       + n1_b[t]);
    o[t + 256] = f2bf((v1 - mu) * rstd * n1_w[t + 256] + n1_b[t + 256]);
    o[t + 512] = f2bf((v2 - mu) * rstd * n1_w[t + 512] + n1_b[t + 512]);
    return;
  }
  __shared__ float tile[32][33];
  const float* W;
  unsigned short* Wt;
  int K, Nn, bx, by;
  if (bid < 1728) {
    W = qkv_w; Wt = wt_qkv; K = 768; Nn = 2304;
    bx = bid % 72; by = bid / 72;
  } else if (bid < 1728 + 576) {
    const int i = bid - 1728;
    W = proj_w; Wt = wt_proj; K = 768; Nn = 768;
    bx = i % 24; by = i / 24;
  } else if (bid < 1728 + 576 + 2304) {
    const int i = bid - (1728 + 576);
    W = fc1_w; Wt = wt_fc1; K = 768; Nn = 3072;
    bx = i % 96; by = i / 96;
  } else {
    const int i = bid - (1728 + 576 + 2304);
    W = fc2_w; Wt = wt_fc2; K = 3072; Nn = 768;
    bx = i % 24; by = i / 24;
  }
  const int tx = t & 31, ty = t >> 5;
  const int n0 = bx * 32, k0 = by * 32;
#pragma unroll
  for (int i = 0; i < 32; i += 8)
    tile[ty + i][tx] = W[(size_t)(k0 + ty + i) * Nn + n0 + tx];
  __syncthreads();
#pragma unroll
  for (int i = 0; i < 32; i += 8)
    Wt[(size_t)(n0 + ty + i) * K + k0 + tx] = f2bf(tile[tx][ty + i]);
}

// ---------------- LayerNorm (fp32 in -> bf16 out) ----------------
__global__ __launch_bounds__(256) void ln_kernel(const float* __restrict__ x,
                                                 const float* __restrict__ w,
                                                 const float* __restrict__ b,
                                                 unsigned short* __restrict__ out) {
  __shared__ float sbuf[8];
  const int row = blockIdx.x;
  const int t = threadIdx.x;
  const float* xr = x + (size_t)row * C_;
  float v0 = xr[t], v1 = xr[t + 256], v2 = xr[t + 512];
  float s = v0 + v1 + v2;
  float ss = v0 * v0 + v1 * v1 + v2 * v2;
#pragma unroll
  for (int m = 32; m >= 1; m >>= 1) {
    s += __shfl_xor(s, m);
    ss += __shfl_xor(ss, m);
  }
  const int wave = t >> 6, lane = t & 63;
  if (lane == 0) { sbuf[wave] = s; sbuf[4 + wave] = ss; }
  __syncthreads();
  s = sbuf[0] + sbuf[1] + sbuf[2] + sbuf[3];
  ss = sbuf[4] + sbuf[5] + sbuf[6] + sbuf[7];
  const float mu = s * (1.f / C_);
  const float var = ss * (1.f / C_) - mu * mu;
  const float rstd = rsqrtf(var + 1e-6f);
  unsigned short* o = out + (size_t)row * C_;
  o[t]       = f2bf((v0 - mu) * rstd * w[t]       + b[t]);
  o[t + 256] = f2bf((v1 - mu) * rstd * w[t + 256] + b[t + 256]);
  o[t + 512] = f2bf((v2 - mu) * rstd * w[t + 512] + b[t + 512]);
}

// ---------------- GEMM: C = A[M,K] * Bt[N,K]^T + bias, fused epilogue ----------
// Waves arranged WM x (4/WM); per-wave output = MR*16 rows x 64 cols.
// BM = WM*MR*16, BN = (4/WM)*64. BK=32. 3 LDS buffers, depth-2 counted-vmcnt
// prefetch, raw s_barrier, setprio, 2-way-optimal LDS XOR swizzle.
//   qkv/fc1: <4,2> -> 128x128 tile. proj/fc2: <1,4> -> 64x64 tile (768 blocks).
template <int MR, int WM, bool GELU, bool RES, bool OUTF, bool OUTB>
__global__ __launch_bounds__(256) void gemm_bt(const unsigned short* __restrict__ A,
                                               const unsigned short* __restrict__ Bt,
                                               const float* __restrict__ bias,
                                               const float* __restrict__ res,
                                               float* __restrict__ outF,
                                               unsigned short* __restrict__ outB,
                                               int M, int Nn, int K) {
  constexpr int WN = 4 / WM;
  constexpr int BM = WM * MR * 16;
  constexpr int BN = WN * 64;
  constexpr int ACALLS = BM / 64;  // 4096B gload calls per A half-stage
  constexpr int BCALLS = BN / 64;
  constexpr int L = ACALLS + BCALLS;  // loads per stage
  __shared__ unsigned short As[3][BM * 32];
  __shared__ unsigned short Bs[3][BN * 32];
  const int t = threadIdx.x;
  const int lane = t & 63;
  const int wave = t >> 6;
  const int wm = wave / WN, wn = wave % WN;
  const int r15 = lane & 15, g = lane >> 4;

  constexpr int SPX = (BM == 128) ? 4 : 8;   // bm stripes per xcd (M == 4096)
  constexpr int LGS = (BM == 128) ? 2 : 3;
  const int orig = blockIdx.y * gridDim.x + blockIdx.x;
  const int xcd = orig & 7;
  const int j = orig >> 3;
  const int bm = xcd * SPX + (j & (SPX - 1));
  const int bn = j >> LGS;

  f32x4 acc[MR][4];
#pragma unroll
  for (int m = 0; m < MR; ++m)
#pragma unroll
    for (int n = 0; n < 4; ++n) acc[m][n] = (f32x4){0.f, 0.f, 0.f, 0.f};

  const int srow = t >> 2;
  const int schunk = (t & 3) ^ ((t >> 3) & 3);
  const unsigned short* ga0 = A + (size_t)(bm * BM + srow) * K + schunk * 8;
  const unsigned short* gb0 = Bt + (size_t)(bn * BN + srow) * K + schunk * 8;

#define GSTAGE(kt_, buf_)                                                      \
  {                                                                            \
    const unsigned short* ga = ga0 + (kt_)*32;                                 \
    const unsigned short* gb = gb0 + (kt_)*32;                                 \
    _Pragma("unroll") for (int c = 0; c < ACALLS; ++c)                         \
        gload16(ga + (size_t)(c * 64) * K,                                     \
                (char*)As[buf_] + c * 4096 + wave * 1024);                     \
    _Pragma("unroll") for (int c = 0; c < BCALLS; ++c)                         \
        gload16(gb + (size_t)(c * 64) * K,                                     \
                (char*)Bs[buf_] + c * 4096 + wave * 1024);                     \
  }

  const int nk = K >> 5;
  GSTAGE(0, 0);
  GSTAGE(1, 1);

  int aoff[MR], boff[4];
#pragma unroll
  for (int m = 0; m < MR; ++m) {
    const int ar = wm * (MR * 16) + m * 16 + r15;
    aoff[m] = ar * 32 + (g ^ ((ar >> 1) & 3)) * 8;
  }
#pragma unroll
  for (int n = 0; n < 4; ++n) {
    const int rn = wn * 64 + n * 16 + r15;
    boff[n] = rn * 32 + (g ^ ((rn >> 1) & 3)) * 8;
  }

  int rd = 0;
  for (int kt = 0; kt < nk; ++kt) {
    const int rem = nk - kt;
    if (rem >= 2) {
      if constexpr (L == 4) asm volatile("s_waitcnt vmcnt(4)" ::: "memory");
      else if constexpr (L == 3) asm volatile("s_waitcnt vmcnt(3)" ::: "memory");
      else asm volatile("s_waitcnt vmcnt(2)" ::: "memory");
    } else {
      asm volatile("s_waitcnt vmcnt(0)" ::: "memory");
    }
    __builtin_amdgcn_s_barrier();

    short8 af[MR], bf[4];
#pragma unroll
    for (int m = 0; m < MR; ++m)
      af[m] = *(const short8*)(As[rd] + aoff[m]);
#pragma unroll
    for (int n = 0; n < 4; ++n)
      bf[n] = *(const short8*)(Bs[rd] + boff[n]);

    if (kt + 2 < nk) {
      const int wr = (rd + 2 >= 3) ? rd - 1 : rd + 2;  // (kt+2)%3
      GSTAGE(kt + 2, wr);
    }

    asm volatile("s_waitcnt lgkmcnt(0)" ::: "memory");
    __builtin_amdgcn_sched_barrier(0);
    __builtin_amdgcn_s_setprio(1);
#pragma unroll
    for (int m = 0; m < MR; ++m)
#pragma unroll
      for (int n = 0; n < 4; ++n)
        acc[m][n] = __builtin_amdgcn_mfma_f32_16x16x32_bf16(af[m], bf[n], acc[m][n], 0, 0, 0);
    __builtin_amdgcn_s_setprio(0);
    rd = (rd == 2) ? 0 : rd + 1;
  }
#undef GSTAGE

#pragma unroll
  for (int m = 0; m < MR; ++m) {
#pragma unroll
    for (int n = 0; n < 4; ++n) {
#pragma unroll
      for (int r = 0; r < 4; ++r) {
        const int row = bm * BM + wm * (MR * 16) + m * 16 + g * 4 + r;
        const int col = bn * BN + wn * 64 + n * 16 + r15;
        float v = acc[m][n][r] + bias[col];
        if (GELU) v = 0.5f * v * (1.f + erff(v * 0.70710678118654752f));
        if (RES) v += res[(size_t)row * Nn + col];
        if (OUTF) outF[(size_t)row * Nn + col] = v;
        if (OUTB) outB[(size_t)row * Nn + col] = f2bf(v);
      }
    }
  }
}

// ---------------- fused biased attention (R17: R14 kernel + XCD bh-affinity) --
__global__ __launch_bounds__(256) void attn_kernel(const unsigned short* __restrict__ qkv,
                                                   const float* __restrict__ pbias,
                                                   unsigned short* __restrict__ o) {
  __shared__ unsigned short Ks[2][64 * 64];
  __shared__ unsigned short Vt[64 * 64];
  __shared__ unsigned short Ps[4][16 * 64];
  const int t = threadIdx.x, lane = t & 63, wave = t >> 6;
  const int f = blockIdx.y * gridDim.x + blockIdx.x;  // 0..767
  const int xcd = f & 7;
  const int j = f >> 3;                               // 0..95
  const int bh = xcd * 6 + (j % 6);
  const int q0 = (j / 6) * 64;
  const int b = bh / H_, h = bh % H_;
  const int r15 = lane & 15, g = lane >> 4;
  const int qrow = q0 + wave * 16;
  const float LOG2E = 1.44269504088896f;
  const float QS = 0.125f * 1.44269504088896f;  // SCALE * log2(e)
  const int NT = N_ / 64;

  short8 aq[2];
  {
    const unsigned short* qp =
        qkv + (size_t)(b * N_ + qrow + r15) * (3 * C_) + h * D_ + g * 8;
    const ushort8 r0 = *(const ushort8*)qp;
    const ushort8 r1 = *(const ushort8*)(qp + 32);
#pragma unroll
    for (int jj = 0; jj < 8; ++jj) {
      aq[0][jj] = (short)f2bf(bf2f(r0[jj]) * QS);
      aq[1][jj] = (short)f2bf(bf2f(r1[jj]) * QS);
    }
  }
  short8 ones;
#pragma unroll
  for (int jj = 0; jj < 8; ++jj) ones[jj] = (short)0x3F80;

  f32x4 oacc[4], lacc;
#pragma unroll
  for (int n = 0; n < 4; ++n) oacc[n] = (f32x4){0.f, 0.f, 0.f, 0.f};
  lacc = (f32x4){0.f, 0.f, 0.f, 0.f};
  float m_run[4];
#pragma unroll
  for (int r = 0; r < 4; ++r) m_run[r] = -1e30f;

  const unsigned short* kbase = qkv + (size_t)b * N_ * (3 * C_) + C_ + h * D_;
  const unsigned short* vbase = qkv + (size_t)b * N_ * (3 * C_) + 2 * C_ + h * D_;

  const float* bp[4];
#pragma unroll
  for (int r = 0; r < 4; ++r)
    bp[r] = pbias + (size_t)b * N_ * N_ + (size_t)(qrow + g * 4 + r) * N_ + r15;

  const int krow = t >> 3;
  const int kchunk = (t & 7) ^ (krow & 7);
  const int vp = t & 31;
  const int vq = t >> 5;
  const int vkey = vp * 2, vd0 = vq * 8;

#define KSTAGE(kb_, nb_)                                                       \
  {                                                                            \
    const unsigned short* kg =                                                 \
        kbase + (size_t)((kb_)*64 + krow) * (3 * C_) + kchunk * 8;             \
    gload16(kg, (char*)Ks[nb_] + wave * 1024);                                 \
    gload16(kg + (size_t)32 * (3 * C_), (char*)Ks[nb_] + wave * 1024 + 4096);  \
  }

#define VWRITE(va_, vb_)                                                             \
  {                                                                                  \
    char* vdst = (char*)Vt;                                                          \
    _Pragma("unroll") for (int jj = 0; jj < 8; ++jj) {                               \
      const int d = vd0 + jj;                                                        \
      const unsigned int pack =                                                      \
          (unsigned int)(va_)[jj] | ((unsigned int)(vb_)[jj] << 16);                 \
      *(unsigned int*)(vdst + d * 128 + (((vp >> 2) ^ (d & 7)) << 4) +               \
                       (vp & 3) * 4) = pack;                                         \
    }                                                                                \
  }

  KSTAGE(0, 0);
  ushort8 va, vb2;
  {
    const unsigned short* vg = vbase + (size_t)vkey * (3 * C_) + vd0;
    va = *(const ushort8*)vg;
    vb2 = *(const ushort8*)(vg + 3 * C_);
  }
  float bcur[4][4], bnext[4][4];
#pragma unroll
  for (int n = 0; n < 4; ++n)
#pragma unroll
    for (int r = 0; r < 4; ++r) bcur[n][r] = bp[r][n * 16];

  for (int kb = 0; kb < NT; ++kb) {
    const int cur = kb & 1;
    __syncthreads();  // K[kb] staged & visible; all waves' PV[kb-1] complete

    VWRITE(va, vb2);

    const bool more = (kb + 1 < NT);
    if (more) {
      KSTAGE(kb + 1, cur ^ 1);
      const unsigned short* vg =
          vbase + (size_t)((kb + 1) * 64 + vkey) * (3 * C_) + vd0;
      va = *(const ushort8*)vg;
      vb2 = *(const ushort8*)(vg + 3 * C_);
#pragma unroll
      for (int n = 0; n < 4; ++n)
#pragma unroll
        for (int r = 0; r < 4; ++r) bnext[n][r] = bp[r][64 + n * 16];
    }
#pragma unroll
    for (int r = 0; r < 4; ++r) bp[r] += 64;

    const unsigned short* Ksc = Ks[cur];
    f32x4 sacc[4];
#pragma unroll
    for (int n = 0; n < 4; ++n) sacc[n] = (f32x4){0.f, 0.f, 0.f, 0.f};
    __builtin_amdgcn_s_setprio(1);
#pragma unroll
    for (int kk = 0; kk < 2; ++kk) {
#pragma unroll
      for (int n = 0; n < 4; ++n) {
        short8 bk = *(const short8*)(Ksc + (n * 16 + r15) * 64 +
                                     (((kk * 4 + g) ^ (r15 & 7)) << 3));
        sacc[n] = __builtin_amdgcn_mfma_f32_16x16x32_bf16(aq[kk], bk, sacc[n], 0, 0, 0);
      }
    }
    __builtin_amdgcn_s_setprio(0);

    float p[4][4], tm[4];
#pragma unroll
    for (int n = 0; n < 4; ++n)
#pragma unroll
      for (int r = 0; r < 4; ++r)
        p[n][r] = fmaf(bcur[n][r], LOG2E, sacc[n][r]);
#pragma unroll
    for (int r = 0; r < 4; ++r)
      tm[r] = fmaxf(fmaxf(p[0][r], p[1][r]), fmaxf(p[2][r], p[3][r]));
#pragma unroll
    for (int r = 0; r < 4; ++r) {
      tm[r] = fmaxf(tm[r], __shfl_xor(tm[r], 1));
      tm[r] = fmaxf(tm[r], __shfl_xor(tm[r], 2));
      tm[r] = fmaxf(tm[r], __shfl_xor(tm[r], 4));
      tm[r] = fmaxf(tm[r], __shfl_xor(tm[r], 8));
    }
    int need = 0;
#pragma unroll
    for (int r = 0; r < 4; ++r) need |= (tm[r] > m_run[r] + 8.0f);
    if (__any(need)) {
#pragma unroll
      for (int r = 0; r < 4; ++r) {
        const float mn = fmaxf(m_run[r], tm[r]);
        const float corr = ex2(m_run[r] - mn);
        m_run[r] = mn;
        lacc[r] *= corr;
#pragma unroll
        for (int n = 0; n < 4; ++n) oacc[n][r] *= corr;
      }
    }
#pragma unroll
    for (int n = 0; n < 4; ++n)
#pragma unroll
      for (int r = 0; r < 4; ++r) p[n][r] = ex2(p[n][r] - m_run[r]);

    unsigned short* Psw = Ps[wave];
#pragma unroll
    for (int n = 0; n < 4; ++n)
#pragma unroll
      for (int r = 0; r < 4; ++r) {
        const int row = g * 4 + r, col = n * 16 + r15;
        Psw[row * 64 + (((col >> 3) ^ (row & 7)) << 3) + (col & 7)] = f2bf(p[n][r]);
      }

    asm volatile("s_waitcnt lgkmcnt(0)" ::: "memory");
    __builtin_amdgcn_s_barrier();
    __builtin_amdgcn_sched_barrier(0);

    __builtin_amdgcn_s_setprio(1);
#pragma unroll
    for (int kk = 0; kk < 2; ++kk) {
      short8 ap = *(const short8*)(Psw + r15 * 64 + (((kk * 4 + g) ^ (r15 & 7)) << 3));
      lacc = __builtin_amdgcn_mfma_f32_16x16x32_bf16(ap, ones, lacc, 0, 0, 0);
#pragma unroll
      for (int n = 0; n < 4; ++n) {
        short8 bv = *(const short8*)(Vt + (n * 16 + r15) * 64 +
                                     (((kk * 4 + g) ^ (r15 & 7)) << 3));
        oacc[n] = __builtin_amdgcn_mfma_f32_16x16x32_bf16(ap, bv, oacc[n], 0, 0, 0);
      }
    }
    __builtin_amdgcn_s_setprio(0);

    if (more) {
#pragma unroll
      for (int n = 0; n < 4; ++n)
#pragma unroll
        for (int r = 0; r < 4; ++r) bcur[n][r] = bnext[n][r];
    }
  }
#undef KSTAGE
#undef VWRITE

  float rl[4];
#pragma unroll
  for (int r = 0; r < 4; ++r) rl[r] = frcp(lacc[r]);
#pragma unroll
  for (int n = 0; n < 4; ++n) {
#pragma unroll
    for (int r = 0; r < 4; ++r) {
      const int row = qrow + g * 4 + r;
      const float v = oacc[n][r] * rl[r];
      o[(size_t)(b * N_ + row) * C_ + h * D_ + n * 16 + r15] = f2bf(v);
    }
  }
}

// ---------------- launcher ----------------
extern "C" void kernel_launch(void* const* d_in, const int* in_sizes, int n_in,
                              void* d_out, int out_size, void* d_ws, size_t ws_size,
                              hipStream_t stream) {
  const float* x      = (const float*)d_in[0];
  const float* pbias  = (const float*)d_in[1];
  const float* qkv_w  = (const float*)d_in[2];
  const float* qkv_b  = (const float*)d_in[3];
  const float* proj_w = (const float*)d_in[4];
  const float* proj_b = (const float*)d_in[5];
  const float* n1_w   = (const float*)d_in[6];
  const float* n1_b   = (const float*)d_in[7];
  const float* n2_w   = (const float*)d_in[8];
  const float* n2_b   = (const float*)d_in[9];
  const float* fc1_w  = (const float*)d_in[10];
  const float* fc1_b  = (const float*)d_in[11];
  const float* fc2_w  = (const float*)d_in[12];
  const float* fc2_b  = (const float*)d_in[13];
  float* out = (float*)d_out;

  char* ws = (char*)d_ws;
  unsigned short* wt_qkv  = (unsigned short*)(ws + 0);          // 2304x768 bf16
  unsigned short* wt_proj = (unsigned short*)(ws + 3538944);    // 768x768
  unsigned short* wt_fc1  = (unsigned short*)(ws + 4718592);    // 3072x768
  unsigned short* wt_fc2  = (unsigned short*)(ws + 9437184);    // 768x3072
  float*          x2      = (float*)(ws + 14155776);            // 4096x768 fp32
  unsigned short* h1      = (unsigned short*)(ws + 26738688);   // 4096x768 bf16
  unsigned short* qkvb    = (unsigned short*)(ws + 33030144);   // 4096x2304 bf16

  prologue_kernel<<<6912 + 4096, 256, 0, stream>>>(
      qkv_w, proj_w, fc1_w, fc2_w, wt_qkv, wt_proj, wt_fc1, wt_fc2,
      x, n1_w, n1_b, h1);

  gemm_bt<4, 2, false, false, false, true><<<dim3(32, 18), 256, 0, stream>>>(
      h1, wt_qkv, qkv_b, nullptr, nullptr, qkvb, M_, 3 * C_, C_);
  attn_kernel<<<dim3(N_ / 64, B_ * H_), 256, 0, stream>>>(qkvb, pbias, h1);
  gemm_bt<1, 4, false, true, true, false><<<dim3(64, 12), 256, 0, stream>>>(
      h1, wt_proj, proj_b, x, x2, nullptr, M_, C_, C_);
  ln_kernel<<<M_, 256, 0, stream>>>(x2, n2_w, n2_b, h1);
  gemm_bt<4, 2, true, false, false, true><<<dim3(32, 24), 256, 0, stream>>>(
      h1, wt_fc1, fc1_b, nullptr, nullptr, qkvb, M_, HID_, C_);
  gemm_bt<1, 4, false, true, true, false><<<dim3(64, 12), 256, 0, stream>>>(
      qkvb, wt_fc2, fc2_b, x2, out, nullptr, M_, C_, HID_);
}